// Round 5
// baseline (577.133 us; speedup 1.0000x reference)
//
#include <hip/hip_runtime.h>

// Problem constants
#define NB   16
#define NQ   300
#define ND   256
#define NH   8
#define NP   4
#define NF   2048
#define NHW  10000
#define NWG  100
#define NROW 4800          // NB*NQ

typedef __attribute__((ext_vector_type(8))) short bf16x8;
typedef __attribute__((ext_vector_type(4))) float f32x4;

__device__ __forceinline__ unsigned short f2bf(float f) {
    unsigned u = __builtin_bit_cast(unsigned, f);
    u = (u + 0x7fffu + ((u >> 16) & 1u)) >> 16;   // RNE
    return (unsigned short)u;
}
__device__ __forceinline__ float bf2f(unsigned short h) {
    unsigned u = ((unsigned)h) << 16;
    return __builtin_bit_cast(float, u);
}

// ---------------------------------------------------------------------------
// Tiled transpose+cast: fp32 [K][N] -> bf16 [N][K] for the six GEMM weights.
// 64x64 tiles via LDS (stride 65 -> conflict-free), coalesced reads AND writes.
// ---------------------------------------------------------------------------
__global__ __launch_bounds__(256) void transpose_cast(
    const float* __restrict__ w_in,  const float* __restrict__ w_out,
    const float* __restrict__ w_vp,  const float* __restrict__ w_op,
    const float* __restrict__ w_l1,  const float* __restrict__ w_l2,
    unsigned short* __restrict__ o_in, unsigned short* __restrict__ o_out,
    unsigned short* __restrict__ o_vp, unsigned short* __restrict__ o_op,
    unsigned short* __restrict__ o_l1, unsigned short* __restrict__ o_l2)
{
    __shared__ float ts[64][65];
    int b = blockIdx.x;
    const float* src; unsigned short* dst; int K, N, ncx;
    if      (b < 48)  { src = w_in;  dst = o_in;  K = 256;  N = 768;  ncx = 12; }
    else if (b < 64)  { src = w_out; dst = o_out; K = 256;  N = 256;  ncx = 4;  b -= 48; }
    else if (b < 80)  { src = w_vp;  dst = o_vp;  K = 256;  N = 256;  ncx = 4;  b -= 64; }
    else if (b < 96)  { src = w_op;  dst = o_op;  K = 256;  N = 256;  ncx = 4;  b -= 80; }
    else if (b < 224) { src = w_l1;  dst = o_l1;  K = 256;  N = 2048; ncx = 32; b -= 96; }
    else              { src = w_l2;  dst = o_l2;  K = 2048; N = 256;  ncx = 4;  b -= 224; }
    const int n0 = (b % ncx) * 64, k0 = (b / ncx) * 64;
    const int t = threadIdx.x;
    const int r = t >> 4, c = t & 15;
    #pragma unroll
    for (int j = 0; j < 4; j++) {
        float4 v = *(const float4*)(src + (long)(k0 + j * 16 + r) * N + n0 + c * 4);
        ts[j * 16 + r][c * 4 + 0] = v.x;
        ts[j * 16 + r][c * 4 + 1] = v.y;
        ts[j * 16 + r][c * 4 + 2] = v.z;
        ts[j * 16 + r][c * 4 + 3] = v.w;
    }
    __syncthreads();
    #pragma unroll
    for (int j = 0; j < 4; j++) {
        unsigned short o[4];
        #pragma unroll
        for (int i = 0; i < 4; i++)
            o[i] = f2bf(ts[c * 4 + i][j * 16 + r]);
        *(uint2*)(dst + (long)(n0 + j * 16 + r) * K + k0 + c * 4) = *(uint2*)o;
    }
}

// ---------------------------------------------------------------------------
// Head weights: concat ref/off/attw -> bf16 [128][256] + fp32 bias[128].
// ---------------------------------------------------------------------------
__global__ __launch_bounds__(256) void prep_head(
    const float* __restrict__ rw, const float* __restrict__ rb,
    const float* __restrict__ ow, const float* __restrict__ ob,
    const float* __restrict__ aw, const float* __restrict__ ab,
    unsigned short* __restrict__ o_hd, float* __restrict__ o_hb)
{
    int id = blockIdx.x * 256 + threadIdx.x;
    if (id < 32768) {
        int n = id >> 8, k = id & 255;
        float v;
        if (n < 2)       v = rw[k * 2 + n];
        else if (n < 66) v = ow[k * 64 + (n - 2)];
        else if (n < 98) v = aw[k * 32 + (n - 66)];
        else             v = 0.0f;
        o_hd[id] = f2bf(v);
        return;
    }
    id -= 32768;
    if (id < 128) {
        float v;
        if (id < 2)       v = rb[id];
        else if (id < 66) v = ob[id - 2];
        else if (id < 98) v = ab[id - 66];
        else              v = 0.0f;
        o_hb[id] = v;
    }
}

// ---------------------------------------------------------------------------
// bf16 MFMA GEMM: C[M,N] = A[M,K](fp32) * Bt[N,K](bf16)^T + bias, opt ReLU,
// fp32/bf16 out. Tile TM x 128, BK=32, 256 threads (4 waves, (TM/2)x64 each).
// Staging uses FLAT-CONTIGUOUS lane mapping: each load instruction's 64 lanes
// cover 16 consecutive cache lines (vs 64 scattered). Double-buffered LDS,
// one barrier/iter, loads for iter k+1 issued before MFMA of iter k.
// MFMA operands swapped -> thread owns C row l16, 4 consecutive cols:
// register-direct coalesced epilogue (16 lines/store-inst).
// SPLITK>1: z-blocks over K, fp32 atomicAdd epilogue (bias z==0 only;
// output pre-zeroed; no ReLU).
// ---------------------------------------------------------------------------
template <int RELU, int OUTBF, int SPLITK, int TM>
__global__ __launch_bounds__(256, (TM == 64) ? 4 : 3) void gemm_bt(
    const float* __restrict__ A, const unsigned short* __restrict__ Bt,
    const float* __restrict__ bias, void* __restrict__ Cout,
    int M, int N, int K)
{
    constexpr int AI = TM / 32;          // A float4-loads per thread
    constexpr int NI = TM / 32;          // A-frags per wave
    __shared__ unsigned short As[2][TM][40];
    __shared__ unsigned short Bs[2][128][40];
    const int t    = threadIdx.x;
    const long m0  = (long)blockIdx.y * TM;
    const int  n0  = blockIdx.x * 128;
    const int  wave = t >> 6, lane = t & 63;
    const int  wm  = (wave >> 1) * (TM / 2);
    const int  wn  = (wave & 1) << 6;
    const int  l16 = lane & 15, quad = lane >> 4;
    const int  arow = t >> 3, acol = (t & 7) << 2;   // A: row j*32+arow, col acol
    const int  brow = t >> 2, bcol = (t & 3) << 3;   // B: row j*64+brow, col bcol

    f32x4 acc[NI][4] = {};

    const int kChunk = K / SPLITK;
    const int kBeg   = (SPLITK > 1) ? blockIdx.z * kChunk : 0;
    const int nk     = kChunk / 32;

    float4 fa[AI];
    uint4  fb[2];

    auto loadAB = [&](int kt) {
        const int k0 = kBeg + kt * 32;
        #pragma unroll
        for (int j = 0; j < AI; j++) {
            const long r = m0 + j * 32 + arow;
            fa[j] = (r < M) ? *(const float4*)(A + r * (long)K + k0 + acol)
                            : make_float4(0.f, 0.f, 0.f, 0.f);
        }
        #pragma unroll
        for (int j = 0; j < 2; j++)      // N % 128 == 0 -> always in-bounds
            fb[j] = *(const uint4*)(Bt + (long)(n0 + j * 64 + brow) * K + k0 + bcol);
    };
    auto storeLDS = [&](int buf) {
        #pragma unroll
        for (int j = 0; j < AI; j++) {
            unsigned short ta[4] = {f2bf(fa[j].x), f2bf(fa[j].y),
                                    f2bf(fa[j].z), f2bf(fa[j].w)};
            *(uint2*)&As[buf][j * 32 + arow][acol] = *(uint2*)ta;
        }
        #pragma unroll
        for (int j = 0; j < 2; j++)
            *(uint4*)&Bs[buf][j * 64 + brow][bcol] = fb[j];
    };

    loadAB(0);
    storeLDS(0);
    __syncthreads();

    for (int kt = 0; kt < nk; kt++) {
        const int cur = kt & 1;
        if (kt + 1 < nk) loadAB(kt + 1);          // prefetch next chunk

        bf16x8 af[NI], bfr[4];
        #pragma unroll
        for (int i = 0; i < NI; i++)
            af[i] = *(const bf16x8*)&As[cur][wm + i * 16 + l16][quad * 8];
        #pragma unroll
        for (int j = 0; j < 4; j++)
            bfr[j] = *(const bf16x8*)&Bs[cur][wn + j * 16 + l16][quad * 8];
        #pragma unroll
        for (int i = 0; i < NI; i++)
            #pragma unroll
            for (int j = 0; j < 4; j++)
                acc[i][j] = __builtin_amdgcn_mfma_f32_16x16x32_bf16(
                    bfr[j], af[i], acc[i][j], 0, 0, 0);   // swapped operands

        if (kt + 1 < nk) {
            storeLDS(cur ^ 1);
            __syncthreads();
        }
    }

    float4 bj[4];
    #pragma unroll
    for (int j = 0; j < 4; j++)
        bj[j] = *(const float4*)&bias[n0 + wn + j * 16 + quad * 4];

    if (SPLITK > 1) {
        const float bscale = (blockIdx.z == 0) ? 1.0f : 0.0f;
        #pragma unroll
        for (int i = 0; i < NI; i++) {
            const long gr = m0 + wm + i * 16 + l16;
            if (gr < M) {
                #pragma unroll
                for (int j = 0; j < 4; j++) {
                    float* cp = (float*)Cout + gr * N + n0 + wn + j * 16 + quad * 4;
                    atomicAdd(cp + 0, acc[i][j][0] + bscale * bj[j].x);
                    atomicAdd(cp + 1, acc[i][j][1] + bscale * bj[j].y);
                    atomicAdd(cp + 2, acc[i][j][2] + bscale * bj[j].z);
                    atomicAdd(cp + 3, acc[i][j][3] + bscale * bj[j].w);
                }
            }
        }
        return;
    }

    #pragma unroll
    for (int i = 0; i < NI; i++) {
        const long gr = m0 + wm + i * 16 + l16;
        if (gr < M) {
            #pragma unroll
            for (int j = 0; j < 4; j++) {
                float4 v;
                v.x = acc[i][j][0] + bj[j].x;
                v.y = acc[i][j][1] + bj[j].y;
                v.z = acc[i][j][2] + bj[j].z;
                v.w = acc[i][j][3] + bj[j].w;
                if (RELU) {
                    v.x = fmaxf(v.x, 0.f); v.y = fmaxf(v.y, 0.f);
                    v.z = fmaxf(v.z, 0.f); v.w = fmaxf(v.w, 0.f);
                }
                const int gc = n0 + wn + j * 16 + quad * 4;
                if (OUTBF) {
                    unsigned short o[4] = {f2bf(v.x), f2bf(v.y), f2bf(v.z), f2bf(v.w)};
                    *(uint2*)((unsigned short*)Cout + gr * N + gc) = *(uint2*)o;
                } else {
                    *(float4*)((float*)Cout + gr * N + gc) = v;
                }
            }
        }
    }
}

// ---------------------------------------------------------------------------
// MFMA self-attention. Grid (5 q-tiles, 128 b*h). Block = 256 thr = 4 waves;
// wave w owns q-rows [q0+16w, q0+16w+16).
// ---------------------------------------------------------------------------
__global__ __launch_bounds__(256) void attn_kernel(
    const float* __restrict__ qkv, float* __restrict__ sa)
{
    __shared__ union {
        struct {
            unsigned short Ks[304][40];   // 24,320 B
            unsigned short Qs[64][40];    //  5,120 B
        } s;
        unsigned short Ps[4][16][328];    // 41,984 B
    } u;
    __shared__ unsigned short Vt[32][328]; // 20,992 B  (total 62,976 B)

    const int bh = blockIdx.y;            // b*8 + h
    const int b  = bh >> 3, h = bh & 7;
    const int q0 = blockIdx.x * 64;
    const int t  = threadIdx.x;

    for (int idx = t; idx < 304 * 8; idx += 256) {
        const int r = idx >> 3, c4 = (idx & 7) << 2;
        if (r < NQ) {
            const float4 kv = *(const float4*)(qkv + ((long)(b * NQ + r)) * 768 + 256 + h * 32 + c4);
            u.s.Ks[r][c4 + 0] = f2bf(kv.x); u.s.Ks[r][c4 + 1] = f2bf(kv.y);
            u.s.Ks[r][c4 + 2] = f2bf(kv.z); u.s.Ks[r][c4 + 3] = f2bf(kv.w);
        } else {
            u.s.Ks[r][c4 + 0] = 0; u.s.Ks[r][c4 + 1] = 0;
            u.s.Ks[r][c4 + 2] = 0; u.s.Ks[r][c4 + 3] = 0;
        }
    }
    for (int idx = t; idx < NQ * 8; idx += 256) {
        const int key = idx >> 3, dq = (idx & 7) << 2;
        const float4 vv = *(const float4*)(qkv + ((long)(b * NQ + key)) * 768 + 512 + h * 32 + dq);
        Vt[dq + 0][key] = f2bf(vv.x); Vt[dq + 1][key] = f2bf(vv.y);
        Vt[dq + 2][key] = f2bf(vv.z); Vt[dq + 3][key] = f2bf(vv.w);
    }
    for (int idx = t; idx < 32 * 20; idx += 256)   // zero keys 300..319
        Vt[idx / 20][300 + idx % 20] = 0;
    for (int idx = t; idx < 64 * 8; idx += 256) {
        const int r = idx >> 3, c4 = (idx & 7) << 2;
        const int q = q0 + r;
        if (q < NQ) {
            const float4 qv = *(const float4*)(qkv + ((long)(b * NQ + q)) * 768 + h * 32 + c4);
            u.s.Qs[r][c4 + 0] = f2bf(qv.x); u.s.Qs[r][c4 + 1] = f2bf(qv.y);
            u.s.Qs[r][c4 + 2] = f2bf(qv.z); u.s.Qs[r][c4 + 3] = f2bf(qv.w);
        } else {
            u.s.Qs[r][c4 + 0] = 0; u.s.Qs[r][c4 + 1] = 0;
            u.s.Qs[r][c4 + 2] = 0; u.s.Qs[r][c4 + 3] = 0;
        }
    }
    __syncthreads();

    const int wave = t >> 6, lane = t & 63;
    const int l16 = lane & 15, quad = lane >> 4;
    const float scale = 0.1767766952966369f;   // 1/sqrt(32)

    const bf16x8 aq = *(const bf16x8*)&u.s.Qs[wave * 16 + l16][quad * 8];
    f32x4 sacc[19];
    #pragma unroll
    for (int kt = 0; kt < 19; kt++) {
        const bf16x8 bk = *(const bf16x8*)&u.s.Ks[kt * 16 + l16][quad * 8];
        sacc[kt] = __builtin_amdgcn_mfma_f32_16x16x32_bf16(
            aq, bk, (f32x4){0.f, 0.f, 0.f, 0.f}, 0, 0, 0);
    }

    float inv[4];
    #pragma unroll
    for (int r = 0; r < 4; r++) {
        float m = -1e30f;
        #pragma unroll
        for (int kt = 0; kt < 19; kt++) {
            float s = sacc[kt][r] * scale;
            if (kt == 18 && l16 >= 12) s = -1e30f;    // keys 300..303 invalid
            sacc[kt][r] = s;
            m = fmaxf(m, s);
        }
        m = fmaxf(m, __shfl_xor(m, 1)); m = fmaxf(m, __shfl_xor(m, 2));
        m = fmaxf(m, __shfl_xor(m, 4)); m = fmaxf(m, __shfl_xor(m, 8));
        float sum = 0.f;
        #pragma unroll
        for (int kt = 0; kt < 19; kt++) {
            float p = __expf(sacc[kt][r] - m);
            sacc[kt][r] = p;
            sum += p;
        }
        sum += __shfl_xor(sum, 1); sum += __shfl_xor(sum, 2);
        sum += __shfl_xor(sum, 4); sum += __shfl_xor(sum, 8);
        inv[r] = 1.0f / sum;
    }

    __syncthreads();   // all waves done with Ks/Qs before Ps overwrites them

    #pragma unroll
    for (int kt = 0; kt < 19; kt++)
        #pragma unroll
        for (int r = 0; r < 4; r++)
            u.Ps[wave][quad * 4 + r][kt * 16 + l16] = f2bf(sacc[kt][r] * inv[r]);
    #pragma unroll
    for (int r = 0; r < 4; r++)      // zero pad keys 304..319
        u.Ps[wave][quad * 4 + r][304 + l16] = 0;

    f32x4 o0 = {0.f, 0.f, 0.f, 0.f}, o1 = {0.f, 0.f, 0.f, 0.f};
    #pragma unroll
    for (int kt = 0; kt < 10; kt++) {
        const bf16x8 ap  = *(const bf16x8*)&u.Ps[wave][l16][kt * 32 + quad * 8];
        const bf16x8 bv0 = *(const bf16x8*)&Vt[l16][kt * 32 + quad * 8];
        const bf16x8 bv1 = *(const bf16x8*)&Vt[16 + l16][kt * 32 + quad * 8];
        o0 = __builtin_amdgcn_mfma_f32_16x16x32_bf16(ap, bv0, o0, 0, 0, 0);
        o1 = __builtin_amdgcn_mfma_f32_16x16x32_bf16(ap, bv1, o1, 0, 0, 0);
    }

    #pragma unroll
    for (int r = 0; r < 4; r++) {
        const int q = q0 + wave * 16 + quad * 4 + r;
        if (q < NQ) {
            float* op = sa + ((long)(b * NQ + q)) * ND + h * 32;
            op[l16]      = o0[r];
            op[16 + l16] = o1[r];
        }
    }
}

// ---------------------------------------------------------------------------
// Residual + LayerNorm: one wave per row of 256.
// ---------------------------------------------------------------------------
__global__ __launch_bounds__(256) void residual_ln(
    const float* __restrict__ a, const float* __restrict__ r,
    const float* __restrict__ gam, const float* __restrict__ bet,
    float* __restrict__ out)
{
    const int row  = blockIdx.x * 4 + (threadIdx.x >> 6);
    const int lane = threadIdx.x & 63;
    const long base = (long)row * ND + lane * 4;
    float4 av = *(const float4*)(a + base);
    float4 rv = *(const float4*)(r + base);
    float x0 = av.x + rv.x, x1 = av.y + rv.y, x2 = av.z + rv.z, x3 = av.w + rv.w;
    float s  = x0 + x1 + x2 + x3;
    float s2 = x0 * x0 + x1 * x1 + x2 * x2 + x3 * x3;
    #pragma unroll
    for (int off = 32; off >= 1; off >>= 1) {
        s  += __shfl_xor(s, off);
        s2 += __shfl_xor(s2, off);
    }
    float mean = s * 0.00390625f;
    float var  = s2 * 0.00390625f - mean * mean;
    float rstd = rsqrtf(var + 1e-5f);
    float4 gv = *(const float4*)(gam + lane * 4);
    float4 bv = *(const float4*)(bet + lane * 4);
    float4 o;
    o.x = (x0 - mean) * rstd * gv.x + bv.x;
    o.y = (x1 - mean) * rstd * gv.y + bv.y;
    o.z = (x2 - mean) * rstd * gv.z + bv.z;
    o.w = (x3 - mean) * rstd * gv.w + bv.w;
    *(float4*)(out + base) = o;
}

// ---------------------------------------------------------------------------
// meta from head-GEMM result res[4800][128].
// ---------------------------------------------------------------------------
__global__ __launch_bounds__(256) void meta_kernel(
    const float* __restrict__ res, float* __restrict__ meta)
{
    const int t   = threadIdx.x;
    const int row = blockIdx.x * 8 + (t >> 5);
    const int s   = t & 31;
    const int h   = s >> 2;
    const float* rp = res + (long)row * 128;
    const float rx = 1.f / (1.f + __expf(-rp[0]));
    const float ry = 1.f / (1.f + __expf(-rp[1]));
    const float offx = rp[2 + 2 * s], offy = rp[3 + 2 * s];
    const float a0 = rp[66 + h * 4 + 0], a1 = rp[66 + h * 4 + 1];
    const float a2 = rp[66 + h * 4 + 2], a3 = rp[66 + h * 4 + 3];
    const float mx = fmaxf(fmaxf(a0, a1), fmaxf(a2, a3));
    const float den = __expf(a0 - mx) + __expf(a1 - mx) +
                      __expf(a2 - mx) + __expf(a3 - mx);
    const float awt = __expf(rp[66 + s] - mx) / den;

    const float lx = fminf(fmaxf(rx + offx, 0.f), 1.f) * (NWG - 1);
    const float ly = fminf(fmaxf(ry + offy, 0.f), 1.f) * (NWG - 1);
    const float fx = floorf(lx), fy = floorf(ly);
    int x0 = (int)fx; x0 = min(max(x0, 0), NWG - 1);
    int y0 = (int)fy; y0 = min(max(y0, 0), NWG - 1);
    const int x1 = min(x0 + 1, NWG - 1);
    const int y1 = min(y0 + 1, NWG - 1);
    const float wx1 = lx - fx, wx0 = 1.f - wx1;
    const float wy1 = ly - fy, wy0 = 1.f - wy1;
    float4 m0, m1;
    m0.x = __int_as_float(y0 * NWG + x0);
    m0.y = __int_as_float(y0 * NWG + x1);
    m0.z = __int_as_float(y1 * NWG + x0);
    m0.w = __int_as_float(y1 * NWG + x1);
    m1.x = awt * wx0 * wy0;
    m1.y = awt * wx1 * wy0;
    m1.z = awt * wx0 * wy1;
    m1.w = awt * wx1 * wy1;
    float* mp = meta + (long)row * 256 + s * 8;
    *(float4*)mp       = m0;
    *(float4*)(mp + 4) = m1;
}

// ---------------------------------------------------------------------------
// Deformable gather: block per (b,q); thread (h = t>>5, d = t&31).
// ---------------------------------------------------------------------------
__global__ __launch_bounds__(256) void deform_gather(
    const float* __restrict__ meta, const unsigned short* __restrict__ vals,
    float* __restrict__ ca)
{
    const int row = blockIdx.x;           // b*300+q
    const int b = row / NQ;
    __shared__ float ms[256];
    const int t = threadIdx.x;
    ms[t] = meta[(long)row * 256 + t];
    __syncthreads();
    const int h = t >> 5, d = t & 31;
    const unsigned short* vb = vals + (long)b * NHW * ND + h * 32 + d;
    float acc = 0.f;
    #pragma unroll
    for (int p = 0; p < NP; p++) {
        const float* mp = ms + h * 32 + p * 8;
        const int i00 = __float_as_int(mp[0]);
        const int i01 = __float_as_int(mp[1]);
        const int i10 = __float_as_int(mp[2]);
        const int i11 = __float_as_int(mp[3]);
        acc += mp[4] * bf2f(vb[(long)i00 * ND]);
        acc += mp[5] * bf2f(vb[(long)i01 * ND]);
        acc += mp[6] * bf2f(vb[(long)i10 * ND]);
        acc += mp[7] * bf2f(vb[(long)i11 * ND]);
    }
    ca[(long)row * ND + t] = acc;
}

// ---------------------------------------------------------------------------
extern "C" void kernel_launch(void* const* d_in, const int* in_sizes, int n_in,
                              void* d_out, int out_size, void* d_ws, size_t ws_size,
                              hipStream_t stream)
{
    (void)in_sizes; (void)n_in; (void)out_size; (void)ws_size;
    const float* tgt   = (const float*)d_in[0];
    const float* mem   = (const float*)d_in[1];
    const float* inpw  = (const float*)d_in[2];
    const float* inpb  = (const float*)d_in[3];
    const float* outw  = (const float*)d_in[4];
    const float* outb  = (const float*)d_in[5];
    const float* n1g   = (const float*)d_in[6];
    const float* n1b   = (const float*)d_in[7];
    const float* refw  = (const float*)d_in[8];
    const float* refb  = (const float*)d_in[9];
    const float* offw  = (const float*)d_in[10];
    const float* offb  = (const float*)d_in[11];
    const float* attww = (const float*)d_in[12];
    const float* attwb = (const float*)d_in[13];
    const float* vpw   = (const float*)d_in[14];
    const float* vpb   = (const float*)d_in[15];
    const float* opw   = (const float*)d_in[16];
    const float* opb   = (const float*)d_in[17];
    const float* n2g   = (const float*)d_in[18];
    const float* n2b   = (const float*)d_in[19];
    const float* l1w   = (const float*)d_in[20];
    const float* l1b   = (const float*)d_in[21];
    const float* l2w   = (const float*)d_in[22];
    const float* l2b   = (const float*)d_in[23];
    const float* n3g   = (const float*)d_in[24];
    const float* n3b   = (const float*)d_in[25];
    float* out = (float*)d_out;

    char* p = (char*)d_ws;
    auto alloc = [&](size_t bytes) {
        char* r = p; p += (bytes + 255) & ~(size_t)255; return (void*)r;
    };
    unsigned short* wtIn   = (unsigned short*)alloc(768 * 256 * 2);
    unsigned short* wtOut  = (unsigned short*)alloc(256 * 256 * 2);
    unsigned short* wtVp   = (unsigned short*)alloc(256 * 256 * 2);
    unsigned short* wtOp   = (unsigned short*)alloc(256 * 256 * 2);
    unsigned short* wtL1   = (unsigned short*)alloc(2048 * 256 * 2);
    unsigned short* wtL2   = (unsigned short*)alloc(256 * 2048 * 2);
    unsigned short* wtHead = (unsigned short*)alloc(128 * 256 * 2);
    float*          headb  = (float*)alloc(128 * 4);
    float* qkv  = (float*)alloc((size_t)NROW * 768 * 4);
    float* sa   = (float*)alloc((size_t)NROW * ND * 4);
    float* x1   = (float*)alloc((size_t)NROW * ND * 4);
    float* x2   = (float*)alloc((size_t)NROW * ND * 4);
    float* tmp  = (float*)alloc((size_t)NROW * ND * 4);
    float* ca   = (float*)alloc((size_t)NROW * ND * 4);
    float* meta = (float*)alloc((size_t)NROW * 256 * 4);
    void* uni = alloc((size_t)NB * NHW * ND * 2);   // vals bf16 / h1 fp32 alias
    unsigned short* vals = (unsigned short*)uni;
    float* h1 = (float*)uni;
    float* res = qkv;   // head-GEMM result [4800][128]; qkv is dead by then

    transpose_cast<<<352, 256, 0, stream>>>(
        inpw, outw, vpw, opw, l1w, l2w,
        wtIn, wtOut, wtVp, wtOp, wtL1, wtL2);
    prep_head<<<129, 256, 0, stream>>>(refw, refb, offw, offb, attww, attwb,
                                       wtHead, headb);

    gemm_bt<0, 0, 1, 64><<<dim3(6, 75), 256, 0, stream>>>(tgt, wtIn, inpb, qkv,
                                                          NROW, 768, 256);
    gemm_bt<0, 1, 1, 128><<<dim3(2, 1250), 256, 0, stream>>>(mem, wtVp, vpb, vals,
                                                             NB * NHW, 256, 256);
    attn_kernel<<<dim3(5, 128), 256, 0, stream>>>(qkv, sa);
    gemm_bt<0, 0, 1, 64><<<dim3(2, 75), 256, 0, stream>>>(sa, wtOut, outb, tmp,
                                                          NROW, 256, 256);
    residual_ln<<<1200, 256, 0, stream>>>(tgt, tmp, n1g, n1b, x1);
    gemm_bt<0, 0, 1, 64><<<dim3(1, 75), 256, 0, stream>>>(x1, wtHead, headb, res,
                                                          NROW, 128, 256);
    meta_kernel<<<600, 256, 0, stream>>>(res, meta);
    deform_gather<<<4800, 256, 0, stream>>>(meta, vals, ca);
    gemm_bt<0, 0, 1, 64><<<dim3(2, 75), 256, 0, stream>>>(ca, wtOp, opb, tmp,
                                                          NROW, 256, 256);
    residual_ln<<<1200, 256, 0, stream>>>(x1, tmp, n2g, n2b, x2);
    gemm_bt<1, 0, 1, 64><<<dim3(16, 75), 256, 0, stream>>>(x2, wtL1, l1b, h1,
                                                           NROW, 2048, 256);
    hipMemsetAsync(tmp, 0, (size_t)NROW * ND * 4, stream);
    gemm_bt<0, 0, 4, 64><<<dim3(2, 75, 4), 256, 0, stream>>>(h1, wtL2, l2b, tmp,
                                                             NROW, 256, 2048);
    residual_ln<<<1200, 256, 0, stream>>>(x2, tmp, n3g, n3b, out);
}

// Round 6
// 516.544 us; speedup vs baseline: 1.1173x; 1.1173x over previous
//
#include <hip/hip_runtime.h>

// Problem constants
#define NB   16
#define NQ   300
#define ND   256
#define NH   8
#define NP   4
#define NF   2048
#define NHW  10000
#define NWG  100
#define NROW 4800          // NB*NQ

typedef __attribute__((ext_vector_type(8))) short bf16x8;
typedef __attribute__((ext_vector_type(4))) float f32x4;

__device__ __forceinline__ unsigned short f2bf(float f) {
    unsigned u = __builtin_bit_cast(unsigned, f);
    u = (u + 0x7fffu + ((u >> 16) & 1u)) >> 16;   // RNE
    return (unsigned short)u;
}
__device__ __forceinline__ float bf2f(unsigned short h) {
    unsigned u = ((unsigned)h) << 16;
    return __builtin_bit_cast(float, u);
}

// ---------------------------------------------------------------------------
// Tiled transpose+cast: fp32 [K][N] -> bf16 [N][K] for the six GEMM weights.
// ---------------------------------------------------------------------------
__global__ __launch_bounds__(256) void transpose_cast(
    const float* __restrict__ w_in,  const float* __restrict__ w_out,
    const float* __restrict__ w_vp,  const float* __restrict__ w_op,
    const float* __restrict__ w_l1,  const float* __restrict__ w_l2,
    unsigned short* __restrict__ o_in, unsigned short* __restrict__ o_out,
    unsigned short* __restrict__ o_vp, unsigned short* __restrict__ o_op,
    unsigned short* __restrict__ o_l1, unsigned short* __restrict__ o_l2)
{
    __shared__ float ts[64][65];
    int b = blockIdx.x;
    const float* src; unsigned short* dst; int K, N, ncx;
    if      (b < 48)  { src = w_in;  dst = o_in;  K = 256;  N = 768;  ncx = 12; }
    else if (b < 64)  { src = w_out; dst = o_out; K = 256;  N = 256;  ncx = 4;  b -= 48; }
    else if (b < 80)  { src = w_vp;  dst = o_vp;  K = 256;  N = 256;  ncx = 4;  b -= 64; }
    else if (b < 96)  { src = w_op;  dst = o_op;  K = 256;  N = 256;  ncx = 4;  b -= 80; }
    else if (b < 224) { src = w_l1;  dst = o_l1;  K = 256;  N = 2048; ncx = 32; b -= 96; }
    else              { src = w_l2;  dst = o_l2;  K = 2048; N = 256;  ncx = 4;  b -= 224; }
    const int n0 = (b % ncx) * 64, k0 = (b / ncx) * 64;
    const int t = threadIdx.x;
    const int r = t >> 4, c = t & 15;
    #pragma unroll
    for (int j = 0; j < 4; j++) {
        float4 v = *(const float4*)(src + (long)(k0 + j * 16 + r) * N + n0 + c * 4);
        ts[j * 16 + r][c * 4 + 0] = v.x;
        ts[j * 16 + r][c * 4 + 1] = v.y;
        ts[j * 16 + r][c * 4 + 2] = v.z;
        ts[j * 16 + r][c * 4 + 3] = v.w;
    }
    __syncthreads();
    #pragma unroll
    for (int j = 0; j < 4; j++) {
        unsigned short o[4];
        #pragma unroll
        for (int i = 0; i < 4; i++)
            o[i] = f2bf(ts[c * 4 + i][j * 16 + r]);
        *(uint2*)(dst + (long)(n0 + j * 16 + r) * K + k0 + c * 4) = *(uint2*)o;
    }
}

// ---------------------------------------------------------------------------
// Head weights: concat ref/off/attw -> bf16 [128][256] + fp32 bias[128].
// ---------------------------------------------------------------------------
__global__ __launch_bounds__(256) void prep_head(
    const float* __restrict__ rw, const float* __restrict__ rb,
    const float* __restrict__ ow, const float* __restrict__ ob,
    const float* __restrict__ aw, const float* __restrict__ ab,
    unsigned short* __restrict__ o_hd, float* __restrict__ o_hb)
{
    int id = blockIdx.x * 256 + threadIdx.x;
    if (id < 32768) {
        int n = id >> 8, k = id & 255;
        float v;
        if (n < 2)       v = rw[k * 2 + n];
        else if (n < 66) v = ow[k * 64 + (n - 2)];
        else if (n < 98) v = aw[k * 32 + (n - 66)];
        else             v = 0.0f;
        o_hd[id] = f2bf(v);
        return;
    }
    id -= 32768;
    if (id < 128) {
        float v;
        if (id < 2)       v = rb[id];
        else if (id < 66) v = ob[id - 2];
        else if (id < 98) v = ab[id - 66];
        else              v = 0.0f;
        o_hb[id] = v;
    }
}

// ---------------------------------------------------------------------------
// Dedicated vproj GEMM: C[160000,256](bf16) = A[160000,256](fp32) * Bt^T + b.
// Tile 128x256 -> A read ONCE (single n-pass). 4 waves, each 64x128,
// acc[4][8]. LDS 60KB (2 blocks/CU). Double-buffered, 32 MFMA per wave-iter.
// ---------------------------------------------------------------------------
__global__ __launch_bounds__(256, 2) void gemm_vproj(
    const float* __restrict__ A, const unsigned short* __restrict__ Bt,
    const float* __restrict__ bias, unsigned short* __restrict__ Cout)
{
    __shared__ unsigned short As[2][128][40];
    __shared__ unsigned short Bs[2][256][40];
    const int t    = threadIdx.x;
    const long m0  = (long)blockIdx.x * 128;
    const int  wave = t >> 6, lane = t & 63;
    const int  wm  = (wave >> 1) << 6;   // 0 / 64
    const int  wn  = (wave & 1) << 7;    // 0 / 128
    const int  l16 = lane & 15, quad = lane >> 4;
    const int  arow = t >> 3, acol = (t & 7) << 2;
    const int  brow = t >> 2, bcol = (t & 3) << 3;

    f32x4 acc[4][8] = {};
    float4 fa[4];
    uint4  fb[4];

    auto loadAB = [&](int k0) {
        #pragma unroll
        for (int j = 0; j < 4; j++)
            fa[j] = *(const float4*)(A + (m0 + j * 32 + arow) * 256L + k0 + acol);
        #pragma unroll
        for (int j = 0; j < 4; j++)
            fb[j] = *(const uint4*)(Bt + (j * 64 + brow) * 256L + k0 + bcol);
    };
    auto storeLDS = [&](int buf) {
        #pragma unroll
        for (int j = 0; j < 4; j++) {
            unsigned short ta[4] = {f2bf(fa[j].x), f2bf(fa[j].y),
                                    f2bf(fa[j].z), f2bf(fa[j].w)};
            *(uint2*)&As[buf][j * 32 + arow][acol] = *(uint2*)ta;
        }
        #pragma unroll
        for (int j = 0; j < 4; j++)
            *(uint4*)&Bs[buf][j * 64 + brow][bcol] = fb[j];
    };

    loadAB(0);
    storeLDS(0);
    __syncthreads();

    for (int kt = 0; kt < 8; kt++) {
        const int cur = kt & 1;
        if (kt < 7) loadAB((kt + 1) * 32);

        bf16x8 af[4], bfr[8];
        #pragma unroll
        for (int i = 0; i < 4; i++)
            af[i] = *(const bf16x8*)&As[cur][wm + i * 16 + l16][quad * 8];
        #pragma unroll
        for (int j = 0; j < 8; j++)
            bfr[j] = *(const bf16x8*)&Bs[cur][wn + j * 16 + l16][quad * 8];
        #pragma unroll
        for (int i = 0; i < 4; i++)
            #pragma unroll
            for (int j = 0; j < 8; j++)
                acc[i][j] = __builtin_amdgcn_mfma_f32_16x16x32_bf16(
                    bfr[j], af[i], acc[i][j], 0, 0, 0);   // swapped operands

        if (kt < 7) {
            storeLDS(cur ^ 1);
            __syncthreads();
        }
    }

    float4 bj[8];
    #pragma unroll
    for (int j = 0; j < 8; j++)
        bj[j] = *(const float4*)&bias[wn + j * 16 + quad * 4];

    #pragma unroll
    for (int i = 0; i < 4; i++) {
        const long gr = m0 + wm + i * 16 + l16;
        #pragma unroll
        for (int j = 0; j < 8; j++) {
            const int gc = wn + j * 16 + quad * 4;
            unsigned short o[4] = {f2bf(acc[i][j][0] + bj[j].x),
                                   f2bf(acc[i][j][1] + bj[j].y),
                                   f2bf(acc[i][j][2] + bj[j].z),
                                   f2bf(acc[i][j][3] + bj[j].w)};
            *(uint2*)(Cout + gr * 256 + gc) = *(uint2*)o;
        }
    }
}

// ---------------------------------------------------------------------------
// bf16 MFMA GEMM: C[M,N] = A[M,K](fp32) * Bt[N,K](bf16)^T + bias, opt ReLU,
// fp32/bf16 out. Tile TM x 128, BK=32, 256 threads. Flat-contiguous staging,
// double-buffered LDS, swapped-operand MFMA -> register-direct epilogue.
// SPLITK>1: z-blocks over K write PARTIAL sums to Cout + z*M*N (plain
// stores; bias folded into z==0 partial; summed later; no ReLU).
// ---------------------------------------------------------------------------
template <int RELU, int OUTBF, int SPLITK, int TM>
__global__ __launch_bounds__(256, (TM == 64) ? 4 : 3) void gemm_bt(
    const float* __restrict__ A, const unsigned short* __restrict__ Bt,
    const float* __restrict__ bias, void* __restrict__ Cout,
    int M, int N, int K)
{
    constexpr int AI = TM / 32;
    constexpr int NI = TM / 32;
    __shared__ unsigned short As[2][TM][40];
    __shared__ unsigned short Bs[2][128][40];
    const int t    = threadIdx.x;
    const long m0  = (long)blockIdx.y * TM;
    const int  n0  = blockIdx.x * 128;
    const int  wave = t >> 6, lane = t & 63;
    const int  wm  = (wave >> 1) * (TM / 2);
    const int  wn  = (wave & 1) << 6;
    const int  l16 = lane & 15, quad = lane >> 4;
    const int  arow = t >> 3, acol = (t & 7) << 2;
    const int  brow = t >> 2, bcol = (t & 3) << 3;

    f32x4 acc[NI][4] = {};

    const int kChunk = K / SPLITK;
    const int kBeg   = (SPLITK > 1) ? blockIdx.z * kChunk : 0;
    const int nk     = kChunk / 32;

    float4 fa[AI];
    uint4  fb[2];

    auto loadAB = [&](int kt) {
        const int k0 = kBeg + kt * 32;
        #pragma unroll
        for (int j = 0; j < AI; j++) {
            const long r = m0 + j * 32 + arow;
            fa[j] = (r < M) ? *(const float4*)(A + r * (long)K + k0 + acol)
                            : make_float4(0.f, 0.f, 0.f, 0.f);
        }
        #pragma unroll
        for (int j = 0; j < 2; j++)
            fb[j] = *(const uint4*)(Bt + (long)(n0 + j * 64 + brow) * K + k0 + bcol);
    };
    auto storeLDS = [&](int buf) {
        #pragma unroll
        for (int j = 0; j < AI; j++) {
            unsigned short ta[4] = {f2bf(fa[j].x), f2bf(fa[j].y),
                                    f2bf(fa[j].z), f2bf(fa[j].w)};
            *(uint2*)&As[buf][j * 32 + arow][acol] = *(uint2*)ta;
        }
        #pragma unroll
        for (int j = 0; j < 2; j++)
            *(uint4*)&Bs[buf][j * 64 + brow][bcol] = fb[j];
    };

    loadAB(0);
    storeLDS(0);
    __syncthreads();

    for (int kt = 0; kt < nk; kt++) {
        const int cur = kt & 1;
        if (kt + 1 < nk) loadAB(kt + 1);

        bf16x8 af[NI], bfr[4];
        #pragma unroll
        for (int i = 0; i < NI; i++)
            af[i] = *(const bf16x8*)&As[cur][wm + i * 16 + l16][quad * 8];
        #pragma unroll
        for (int j = 0; j < 4; j++)
            bfr[j] = *(const bf16x8*)&Bs[cur][wn + j * 16 + l16][quad * 8];
        #pragma unroll
        for (int i = 0; i < NI; i++)
            #pragma unroll
            for (int j = 0; j < 4; j++)
                acc[i][j] = __builtin_amdgcn_mfma_f32_16x16x32_bf16(
                    bfr[j], af[i], acc[i][j], 0, 0, 0);

        if (kt + 1 < nk) {
            storeLDS(cur ^ 1);
            __syncthreads();
        }
    }

    float4 bj[4];
    #pragma unroll
    for (int j = 0; j < 4; j++)
        bj[j] = *(const float4*)&bias[n0 + wn + j * 16 + quad * 4];

    float* outp = (float*)Cout;
    float bscale = 1.0f;
    if (SPLITK > 1) {
        outp += (size_t)blockIdx.z * M * N;        // partial buffer z
        bscale = (blockIdx.z == 0) ? 1.0f : 0.0f;
    }

    #pragma unroll
    for (int i = 0; i < NI; i++) {
        const long gr = m0 + wm + i * 16 + l16;
        if (gr < M) {
            #pragma unroll
            for (int j = 0; j < 4; j++) {
                float4 v;
                v.x = acc[i][j][0] + bscale * bj[j].x;
                v.y = acc[i][j][1] + bscale * bj[j].y;
                v.z = acc[i][j][2] + bscale * bj[j].z;
                v.w = acc[i][j][3] + bscale * bj[j].w;
                if (RELU) {
                    v.x = fmaxf(v.x, 0.f); v.y = fmaxf(v.y, 0.f);
                    v.z = fmaxf(v.z, 0.f); v.w = fmaxf(v.w, 0.f);
                }
                const int gc = n0 + wn + j * 16 + quad * 4;
                if (OUTBF) {
                    unsigned short o[4] = {f2bf(v.x), f2bf(v.y), f2bf(v.z), f2bf(v.w)};
                    *(uint2*)((unsigned short*)Cout + gr * N + gc) = *(uint2*)o;
                } else {
                    *(float4*)(outp + gr * N + gc) = v;
                }
            }
        }
    }
}

// ---------------------------------------------------------------------------
// MFMA self-attention. Grid (5 q-tiles, 128 b*h).
// ---------------------------------------------------------------------------
__global__ __launch_bounds__(256) void attn_kernel(
    const float* __restrict__ qkv, float* __restrict__ sa)
{
    __shared__ union {
        struct {
            unsigned short Ks[304][40];
            unsigned short Qs[64][40];
        } s;
        unsigned short Ps[4][16][328];
    } u;
    __shared__ unsigned short Vt[32][328];

    const int bh = blockIdx.y;
    const int b  = bh >> 3, h = bh & 7;
    const int q0 = blockIdx.x * 64;
    const int t  = threadIdx.x;

    for (int idx = t; idx < 304 * 8; idx += 256) {
        const int r = idx >> 3, c4 = (idx & 7) << 2;
        if (r < NQ) {
            const float4 kv = *(const float4*)(qkv + ((long)(b * NQ + r)) * 768 + 256 + h * 32 + c4);
            u.s.Ks[r][c4 + 0] = f2bf(kv.x); u.s.Ks[r][c4 + 1] = f2bf(kv.y);
            u.s.Ks[r][c4 + 2] = f2bf(kv.z); u.s.Ks[r][c4 + 3] = f2bf(kv.w);
        } else {
            u.s.Ks[r][c4 + 0] = 0; u.s.Ks[r][c4 + 1] = 0;
            u.s.Ks[r][c4 + 2] = 0; u.s.Ks[r][c4 + 3] = 0;
        }
    }
    for (int idx = t; idx < NQ * 8; idx += 256) {
        const int key = idx >> 3, dq = (idx & 7) << 2;
        const float4 vv = *(const float4*)(qkv + ((long)(b * NQ + key)) * 768 + 512 + h * 32 + dq);
        Vt[dq + 0][key] = f2bf(vv.x); Vt[dq + 1][key] = f2bf(vv.y);
        Vt[dq + 2][key] = f2bf(vv.z); Vt[dq + 3][key] = f2bf(vv.w);
    }
    for (int idx = t; idx < 32 * 20; idx += 256)
        Vt[idx / 20][300 + idx % 20] = 0;
    for (int idx = t; idx < 64 * 8; idx += 256) {
        const int r = idx >> 3, c4 = (idx & 7) << 2;
        const int q = q0 + r;
        if (q < NQ) {
            const float4 qv = *(const float4*)(qkv + ((long)(b * NQ + q)) * 768 + h * 32 + c4);
            u.s.Qs[r][c4 + 0] = f2bf(qv.x); u.s.Qs[r][c4 + 1] = f2bf(qv.y);
            u.s.Qs[r][c4 + 2] = f2bf(qv.z); u.s.Qs[r][c4 + 3] = f2bf(qv.w);
        } else {
            u.s.Qs[r][c4 + 0] = 0; u.s.Qs[r][c4 + 1] = 0;
            u.s.Qs[r][c4 + 2] = 0; u.s.Qs[r][c4 + 3] = 0;
        }
    }
    __syncthreads();

    const int wave = t >> 6, lane = t & 63;
    const int l16 = lane & 15, quad = lane >> 4;
    const float scale = 0.1767766952966369f;

    const bf16x8 aq = *(const bf16x8*)&u.s.Qs[wave * 16 + l16][quad * 8];
    f32x4 sacc[19];
    #pragma unroll
    for (int kt = 0; kt < 19; kt++) {
        const bf16x8 bk = *(const bf16x8*)&u.s.Ks[kt * 16 + l16][quad * 8];
        sacc[kt] = __builtin_amdgcn_mfma_f32_16x16x32_bf16(
            aq, bk, (f32x4){0.f, 0.f, 0.f, 0.f}, 0, 0, 0);
    }

    float inv[4];
    #pragma unroll
    for (int r = 0; r < 4; r++) {
        float m = -1e30f;
        #pragma unroll
        for (int kt = 0; kt < 19; kt++) {
            float s = sacc[kt][r] * scale;
            if (kt == 18 && l16 >= 12) s = -1e30f;
            sacc[kt][r] = s;
            m = fmaxf(m, s);
        }
        m = fmaxf(m, __shfl_xor(m, 1)); m = fmaxf(m, __shfl_xor(m, 2));
        m = fmaxf(m, __shfl_xor(m, 4)); m = fmaxf(m, __shfl_xor(m, 8));
        float sum = 0.f;
        #pragma unroll
        for (int kt = 0; kt < 19; kt++) {
            float p = __expf(sacc[kt][r] - m);
            sacc[kt][r] = p;
            sum += p;
        }
        sum += __shfl_xor(sum, 1); sum += __shfl_xor(sum, 2);
        sum += __shfl_xor(sum, 4); sum += __shfl_xor(sum, 8);
        inv[r] = 1.0f / sum;
    }

    __syncthreads();

    #pragma unroll
    for (int kt = 0; kt < 19; kt++)
        #pragma unroll
        for (int r = 0; r < 4; r++)
            u.Ps[wave][quad * 4 + r][kt * 16 + l16] = f2bf(sacc[kt][r] * inv[r]);
    #pragma unroll
    for (int r = 0; r < 4; r++)
        u.Ps[wave][quad * 4 + r][304 + l16] = 0;

    f32x4 o0 = {0.f, 0.f, 0.f, 0.f}, o1 = {0.f, 0.f, 0.f, 0.f};
    #pragma unroll
    for (int kt = 0; kt < 10; kt++) {
        const bf16x8 ap  = *(const bf16x8*)&u.Ps[wave][l16][kt * 32 + quad * 8];
        const bf16x8 bv0 = *(const bf16x8*)&Vt[l16][kt * 32 + quad * 8];
        const bf16x8 bv1 = *(const bf16x8*)&Vt[16 + l16][kt * 32 + quad * 8];
        o0 = __builtin_amdgcn_mfma_f32_16x16x32_bf16(ap, bv0, o0, 0, 0, 0);
        o1 = __builtin_amdgcn_mfma_f32_16x16x32_bf16(ap, bv1, o1, 0, 0, 0);
    }

    #pragma unroll
    for (int r = 0; r < 4; r++) {
        const int q = q0 + wave * 16 + quad * 4 + r;
        if (q < NQ) {
            float* op = sa + ((long)(b * NQ + q)) * ND + h * 32;
            op[l16]      = o0[r];
            op[16 + l16] = o1[r];
        }
    }
}

// ---------------------------------------------------------------------------
// Residual + LayerNorm (NPART residual partials summed): one wave per row.
// ---------------------------------------------------------------------------
template <int NPART>
__global__ __launch_bounds__(256) void residual_ln(
    const float* __restrict__ a, const float* __restrict__ r,
    const float* __restrict__ gam, const float* __restrict__ bet,
    float* __restrict__ out, long pstride)
{
    const int row  = blockIdx.x * 4 + (threadIdx.x >> 6);
    const int lane = threadIdx.x & 63;
    const long base = (long)row * ND + lane * 4;
    float4 av = *(const float4*)(a + base);
    float4 rv = *(const float4*)(r + base);
    #pragma unroll
    for (int z = 1; z < NPART; z++) {
        float4 pv = *(const float4*)(r + z * pstride + base);
        rv.x += pv.x; rv.y += pv.y; rv.z += pv.z; rv.w += pv.w;
    }
    float x0 = av.x + rv.x, x1 = av.y + rv.y, x2 = av.z + rv.z, x3 = av.w + rv.w;
    float s  = x0 + x1 + x2 + x3;
    float s2 = x0 * x0 + x1 * x1 + x2 * x2 + x3 * x3;
    #pragma unroll
    for (int off = 32; off >= 1; off >>= 1) {
        s  += __shfl_xor(s, off);
        s2 += __shfl_xor(s2, off);
    }
    float mean = s * 0.00390625f;
    float var  = s2 * 0.00390625f - mean * mean;
    float rstd = rsqrtf(var + 1e-5f);
    float4 gv = *(const float4*)(gam + lane * 4);
    float4 bv = *(const float4*)(bet + lane * 4);
    float4 o;
    o.x = (x0 - mean) * rstd * gv.x + bv.x;
    o.y = (x1 - mean) * rstd * gv.y + bv.y;
    o.z = (x2 - mean) * rstd * gv.z + bv.z;
    o.w = (x3 - mean) * rstd * gv.w + bv.w;
    *(float4*)(out + base) = o;
}

// ---------------------------------------------------------------------------
// meta from head-GEMM result res[4800][128].
// ---------------------------------------------------------------------------
__global__ __launch_bounds__(256) void meta_kernel(
    const float* __restrict__ res, float* __restrict__ meta)
{
    const int t   = threadIdx.x;
    const int row = blockIdx.x * 8 + (t >> 5);
    const int s   = t & 31;
    const int h   = s >> 2;
    const float* rp = res + (long)row * 128;
    const float rx = 1.f / (1.f + __expf(-rp[0]));
    const float ry = 1.f / (1.f + __expf(-rp[1]));
    const float offx = rp[2 + 2 * s], offy = rp[3 + 2 * s];
    const float a0 = rp[66 + h * 4 + 0], a1 = rp[66 + h * 4 + 1];
    const float a2 = rp[66 + h * 4 + 2], a3 = rp[66 + h * 4 + 3];
    const float mx = fmaxf(fmaxf(a0, a1), fmaxf(a2, a3));
    const float den = __expf(a0 - mx) + __expf(a1 - mx) +
                      __expf(a2 - mx) + __expf(a3 - mx);
    const float awt = __expf(rp[66 + s] - mx) / den;

    const float lx = fminf(fmaxf(rx + offx, 0.f), 1.f) * (NWG - 1);
    const float ly = fminf(fmaxf(ry + offy, 0.f), 1.f) * (NWG - 1);
    const float fx = floorf(lx), fy = floorf(ly);
    int x0 = (int)fx; x0 = min(max(x0, 0), NWG - 1);
    int y0 = (int)fy; y0 = min(max(y0, 0), NWG - 1);
    const int x1 = min(x0 + 1, NWG - 1);
    const int y1 = min(y0 + 1, NWG - 1);
    const float wx1 = lx - fx, wx0 = 1.f - wx1;
    const float wy1 = ly - fy, wy0 = 1.f - wy1;
    float4 m0, m1;
    m0.x = __int_as_float(y0 * NWG + x0);
    m0.y = __int_as_float(y0 * NWG + x1);
    m0.z = __int_as_float(y1 * NWG + x0);
    m0.w = __int_as_float(y1 * NWG + x1);
    m1.x = awt * wx0 * wy0;
    m1.y = awt * wx1 * wy0;
    m1.z = awt * wx0 * wy1;
    m1.w = awt * wx1 * wy1;
    float* mp = meta + (long)row * 256 + s * 8;
    *(float4*)mp       = m0;
    *(float4*)(mp + 4) = m1;
}

// ---------------------------------------------------------------------------
// Deformable gather: block per (b,q); thread (h = t>>5, d = t&31).
// ---------------------------------------------------------------------------
__global__ __launch_bounds__(256) void deform_gather(
    const float* __restrict__ meta, const unsigned short* __restrict__ vals,
    float* __restrict__ ca)
{
    const int row = blockIdx.x;
    const int b = row / NQ;
    __shared__ float ms[256];
    const int t = threadIdx.x;
    ms[t] = meta[(long)row * 256 + t];
    __syncthreads();
    const int h = t >> 5, d = t & 31;
    const unsigned short* vb = vals + (long)b * NHW * ND + h * 32 + d;
    float acc = 0.f;
    #pragma unroll
    for (int p = 0; p < NP; p++) {
        const float* mp = ms + h * 32 + p * 8;
        const int i00 = __float_as_int(mp[0]);
        const int i01 = __float_as_int(mp[1]);
        const int i10 = __float_as_int(mp[2]);
        const int i11 = __float_as_int(mp[3]);
        acc += mp[4] * bf2f(vb[(long)i00 * ND]);
        acc += mp[5] * bf2f(vb[(long)i01 * ND]);
        acc += mp[6] * bf2f(vb[(long)i10 * ND]);
        acc += mp[7] * bf2f(vb[(long)i11 * ND]);
    }
    ca[(long)row * ND + t] = acc;
}

// ---------------------------------------------------------------------------
extern "C" void kernel_launch(void* const* d_in, const int* in_sizes, int n_in,
                              void* d_out, int out_size, void* d_ws, size_t ws_size,
                              hipStream_t stream)
{
    (void)in_sizes; (void)n_in; (void)out_size; (void)ws_size;
    const float* tgt   = (const float*)d_in[0];
    const float* mem   = (const float*)d_in[1];
    const float* inpw  = (const float*)d_in[2];
    const float* inpb  = (const float*)d_in[3];
    const float* outw  = (const float*)d_in[4];
    const float* outb  = (const float*)d_in[5];
    const float* n1g   = (const float*)d_in[6];
    const float* n1b   = (const float*)d_in[7];
    const float* refw  = (const float*)d_in[8];
    const float* refb  = (const float*)d_in[9];
    const float* offw  = (const float*)d_in[10];
    const float* offb  = (const float*)d_in[11];
    const float* attww = (const float*)d_in[12];
    const float* attwb = (const float*)d_in[13];
    const float* vpw   = (const float*)d_in[14];
    const float* vpb   = (const float*)d_in[15];
    const float* opw   = (const float*)d_in[16];
    const float* opb   = (const float*)d_in[17];
    const float* n2g   = (const float*)d_in[18];
    const float* n2b   = (const float*)d_in[19];
    const float* l1w   = (const float*)d_in[20];
    const float* l1b   = (const float*)d_in[21];
    const float* l2w   = (const float*)d_in[22];
    const float* l2b   = (const float*)d_in[23];
    const float* n3g   = (const float*)d_in[24];
    const float* n3b   = (const float*)d_in[25];
    float* out = (float*)d_out;

    char* p = (char*)d_ws;
    auto alloc = [&](size_t bytes) {
        char* r = p; p += (bytes + 255) & ~(size_t)255; return (void*)r;
    };
    unsigned short* wtIn   = (unsigned short*)alloc(768 * 256 * 2);
    unsigned short* wtOut  = (unsigned short*)alloc(256 * 256 * 2);
    unsigned short* wtVp   = (unsigned short*)alloc(256 * 256 * 2);
    unsigned short* wtOp   = (unsigned short*)alloc(256 * 256 * 2);
    unsigned short* wtL1   = (unsigned short*)alloc(2048 * 256 * 2);
    unsigned short* wtL2   = (unsigned short*)alloc(256 * 2048 * 2);
    unsigned short* wtHead = (unsigned short*)alloc(128 * 256 * 2);
    float*          headb  = (float*)alloc(128 * 4);
    float* qkv  = (float*)alloc((size_t)NROW * 768 * 4);
    float* sa   = (float*)alloc((size_t)NROW * ND * 4);
    float* x1   = (float*)alloc((size_t)NROW * ND * 4);
    float* x2   = (float*)alloc((size_t)NROW * ND * 4);
    float* tmp  = (float*)alloc((size_t)NROW * ND * 4 * 4);   // 4 split-K partials
    float* ca   = (float*)alloc((size_t)NROW * ND * 4);
    float* meta = (float*)alloc((size_t)NROW * 256 * 4);
    void* uni = alloc((size_t)NB * NHW * ND * 2);   // vals bf16 / h1 fp32 alias
    unsigned short* vals = (unsigned short*)uni;
    float* h1 = (float*)uni;
    float* res = qkv;   // head-GEMM result; qkv dead by then

    transpose_cast<<<352, 256, 0, stream>>>(
        inpw, outw, vpw, opw, l1w, l2w,
        wtIn, wtOut, wtVp, wtOp, wtL1, wtL2);
    prep_head<<<129, 256, 0, stream>>>(refw, refb, offw, offb, attww, attwb,
                                       wtHead, headb);

    gemm_bt<0, 0, 1, 64><<<dim3(6, 75), 256, 0, stream>>>(tgt, wtIn, inpb, qkv,
                                                          NROW, 768, 256);
    gemm_vproj<<<1250, 256, 0, stream>>>(mem, wtVp, vpb, vals);
    attn_kernel<<<dim3(5, 128), 256, 0, stream>>>(qkv, sa);
    gemm_bt<0, 0, 1, 64><<<dim3(2, 75), 256, 0, stream>>>(sa, wtOut, outb, tmp,
                                                          NROW, 256, 256);
    residual_ln<1><<<1200, 256, 0, stream>>>(tgt, tmp, n1g, n1b, x1, 0);
    gemm_bt<0, 0, 1, 64><<<dim3(1, 75), 256, 0, stream>>>(x1, wtHead, headb, res,
                                                          NROW, 128, 256);
    meta_kernel<<<600, 256, 0, stream>>>(res, meta);
    deform_gather<<<4800, 256, 0, stream>>>(meta, vals, ca);
    gemm_bt<0, 0, 1, 64><<<dim3(2, 75), 256, 0, stream>>>(ca, wtOp, opb, tmp,
                                                          NROW, 256, 256);
    residual_ln<1><<<1200, 256, 0, stream>>>(x1, tmp, n2g, n2b, x2, 0);
    gemm_bt<1, 0, 1, 64><<<dim3(16, 75), 256, 0, stream>>>(x2, wtL1, l1b, h1,
                                                           NROW, 2048, 256);
    gemm_bt<0, 0, 4, 64><<<dim3(2, 75, 4), 256, 0, stream>>>(h1, wtL2, l2b, tmp,
                                                             NROW, 256, 2048);
    residual_ln<4><<<1200, 256, 0, stream>>>(x2, tmp, n3g, n3b, out,
                                             (long)NROW * ND);
}